// Round 25
// baseline (122.122 us; speedup 1.0000x reference)
//
#include <hip/hip_runtime.h>
#include <hip/hip_fp8.h>

#define NHALF 4096
#define NROWS 8192
#define D 512
#define BM 128
#define BKB 128                    // B K-step in fp8 bytes
#define NKT (D / BKB)              // 4 K-steps per tile
#define NB (NROWS / BM)            // 64
#define TPB 4                      // j-tiles per block (A-panel reuse)
#define NBLK 544                   // sum over bi of ceil((64-bi)/4) = 8*68
#define CONV_BLOCKS 256

typedef float f32x4 __attribute__((ext_vector_type(4)));

__device__ __forceinline__ const float* row_ptr(const float* __restrict__ src,
                                                const float* __restrict__ tgt, int r) {
    return (r < NHALF) ? (src + (size_t)r * D) : (tgt + (size_t)(r - NHALF) * D);
}

// --- Pass A: convert fp32->fp8 e4m3 via HW v_cvt_pk_fp8_f32 (XOR-swizzle baked)
//     + rowsq + colsum + sumsq + (last block, ticketed) bandwidth scalar ---
__global__ __launch_bounds__(256)
void conv_stats(const float* __restrict__ src, const float* __restrict__ tgt,
                unsigned char* __restrict__ tot8, float* __restrict__ sq,
                float* __restrict__ colsum, double* __restrict__ sumsq,
                unsigned* __restrict__ ticket, float* __restrict__ inv16bw_out) {
    __shared__ float cs_lds[4][512];
    __shared__ float wssq[4];
    __shared__ int lastFlag;
    __shared__ double red[256];
    int t = threadIdx.x, l = t & 63, w = t >> 6;
    int rbase = blockIdx.x * 32 + w * 8;

    float cs[8] = {0.f, 0.f, 0.f, 0.f, 0.f, 0.f, 0.f, 0.f};
    float ssq = 0.f;

    for (int rr = 0; rr < 8; ++rr) {
        int r = rbase + rr;
        const float* p = row_ptr(src, tgt, r) + l * 8;
        float4 v0 = *(const float4*)p;
        float4 v1 = *(const float4*)(p + 4);
        union { unsigned long long u; int i2[2]; } q;
        q.i2[0] = __builtin_amdgcn_cvt_pk_fp8_f32(v0.x, v0.y, 0, false);
        q.i2[0] = __builtin_amdgcn_cvt_pk_fp8_f32(v0.z, v0.w, q.i2[0], true);
        q.i2[1] = __builtin_amdgcn_cvt_pk_fp8_f32(v1.x, v1.y, 0, false);
        q.i2[1] = __builtin_amdgcn_cvt_pk_fp8_f32(v1.z, v1.w, q.i2[1], true);
        unsigned dstu = (unsigned)((l & 48) | ((l & 15) ^ (r & 15)));
        *(unsigned long long*)&tot8[(size_t)r * D + dstu * 8] = q.u;

        float s8 = v0.x*v0.x + v0.y*v0.y + v0.z*v0.z + v0.w*v0.w
                 + v1.x*v1.x + v1.y*v1.y + v1.z*v1.z + v1.w*v1.w;
        ssq += s8;
        cs[0] += v0.x; cs[1] += v0.y; cs[2] += v0.z; cs[3] += v0.w;
        cs[4] += v1.x; cs[5] += v1.y; cs[6] += v1.z; cs[7] += v1.w;
        float rsum = s8;
        for (int off = 32; off > 0; off >>= 1) rsum += __shfl_down(rsum, off);
        if (l == 0) sq[r] = rsum;
    }
#pragma unroll
    for (int j = 0; j < 8; ++j) cs_lds[w][l * 8 + j] = cs[j];
    for (int off = 32; off > 0; off >>= 1) ssq += __shfl_down(ssq, off);
    if (l == 0) wssq[w] = ssq;
    __syncthreads();
    int c0 = t * 2;
    float a = cs_lds[0][c0] + cs_lds[1][c0] + cs_lds[2][c0] + cs_lds[3][c0];
    float b = cs_lds[0][c0+1] + cs_lds[1][c0+1] + cs_lds[2][c0+1] + cs_lds[3][c0+1];
    atomicAdd(&colsum[c0], a);
    atomicAdd(&colsum[c0 + 1], b);
    if (t == 0) atomicAdd(sumsq, (double)(wssq[0] + wssq[1] + wssq[2] + wssq[3]));
    __syncthreads();

    if (t == 0) {
        __threadfence();
        unsigned old = atomicAdd(ticket, 1u);
        lastFlag = (old == CONV_BLOCKS - 1) ? 1 : 0;
    }
    __syncthreads();
    if (lastFlag) {
        float ca = atomicAdd(&colsum[t], 0.f);
        float cb = atomicAdd(&colsum[t + 256], 0.f);
        red[t] = (double)ca * ca + (double)cb * cb;
        __syncthreads();
        for (int s = 128; s > 0; s >>= 1) {
            if (t < s) red[t] += red[t + s];
            __syncthreads();
        }
        if (t == 0) {
            double ssqd = atomicAdd(sumsq, 0.0);
            double m = (double)NROWS;
            double sumL2 = 2.0 * m * ssqd - 2.0 * red[0];
            double bw = sumL2 / (m * m - m) / 4.0;
            inv16bw_out[0] = (float)(1.0 / (16.0 * bw));
        }
    }
}

// --- Pass B: fp8 MFMA, A-panel resident in LDS (64 KB) + 4 j-tiles per block ---
__global__ __launch_bounds__(512, 4)
void mmd_main(const unsigned char* __restrict__ tot8,
              const float* __restrict__ sq, const float* __restrict__ inv16bw_p,
              double* __restrict__ S) {
    int b = blockIdx.x;
    int nb = (b & 7) * (NBLK / 8) + (b >> 3);   // XCD swizzle (544 = 8*68, bijective)
    // decode: row bi, chunk of 4 consecutive j-tiles starting at bj0
    int bi = 0, rem = nb;
    while (rem >= ((67 - bi) >> 2)) { rem -= (67 - bi) >> 2; ++bi; }
    int bj0 = bi + rem * 4;

    // LDS: A panel [128 rows][512 B] (full K) + B tile [128 rows][128 B] = 80 KB exact
    __shared__ __align__(16) unsigned char Al[BM * D];     // 64 KB
    __shared__ __align__(16) unsigned char Bl[BM * BKB];   // 16 KB

    int t = threadIdx.x, l = t & 63, w = t >> 6;
    int wr = w >> 2, wc = w & 3;       // 2x4 wave grid; per-wave 64x32 output
    int m = l & 15, kg = l >> 4;

    const unsigned char* ap = tot8 + (size_t)bi * BM * D;

    auto stage_B = [&](const unsigned char* bb, int kt) {
#pragma unroll
        for (int i = 0; i < 2; ++i) {
            int g = i * 512 + t;           // 0..1023 chunks of 16 B
            int row = g >> 3, ch = g & 7;
            __builtin_amdgcn_global_load_lds(
                (const __attribute__((address_space(1))) void*)(bb + (size_t)row * D + kt * BKB + ch * 16),
                (__attribute__((address_space(3))) void*)(Bl + g * 16),
                16, 0, 0);
        }
    };

    f32x4 acc[4][2];
#pragma unroll
    for (int i = 0; i < 4; ++i)
#pragma unroll
        for (int j = 0; j < 2; ++j)
            acc[i][j] = (f32x4){0.f, 0.f, 0.f, 0.f};

    // Prologue: stage full A panel (verbatim 64 KB) + first B tile-step
#pragma unroll
    for (int i = 0; i < 8; ++i) {
        int g = i * 512 + t;               // 0..4095 chunks of 16 B
        int row = g >> 5, ch = g & 31;
        __builtin_amdgcn_global_load_lds(
            (const __attribute__((address_space(1))) void*)(ap + (size_t)row * D + ch * 16),
            (__attribute__((address_space(3))) void*)(Al + g * 16),
            16, 0, 0);
    }
    const unsigned char* bb = tot8 + (size_t)bj0 * BM * D;
    stage_B(bb, 0);
    __syncthreads();   // drains vmcnt(0): A panel + first B ready

    float inv16bw = inv16bw_p[0];
    float wacc = 0.f;   // lane0-of-wave accumulator across tiles

    auto epilogue = [&](int tile) {
        int bjv = bj0 + tile;
        float coef = 0.f;
        int bjc = bjv;
        if (bjv <= 63) {
            coef = ((bi == bjv) ? 1.f : 2.f) * (((bi < 32) == (bjv < 32)) ? 1.f : -1.f);
        } else bjc = 63;
        float sqj[2];
#pragma unroll
        for (int fj = 0; fj < 2; ++fj) sqj[fj] = sq[bjc * BM + wc * 32 + fj * 16 + m];
        int ib = bi * BM + wr * 64 + kg * 4;
        float local = 0.f;
#pragma unroll
        for (int fi = 0; fi < 4; ++fi) {
            float sqi[4];
#pragma unroll
            for (int j = 0; j < 4; ++j) sqi[j] = sq[ib + fi * 16 + j];
#pragma unroll
            for (int fj = 0; fj < 2; ++fj) {
#pragma unroll
                for (int j = 0; j < 4; ++j) {
                    float L2 = sqi[j] + sqj[fj] - 2.f * acc[fi][fj][j];
                    float u = __expf(-L2 * inv16bw);   // e^{-t/16}
                    float ks = u;
                    u *= u; ks += u;   // e^{-t/8}
                    u *= u; ks += u;   // e^{-t/4}
                    u *= u; ks += u;   // e^{-t/2}
                    u *= u; ks += u;   // e^{-t}
                    if (bi == bjc) {
                        int ig = wr * 64 + fi * 16 + kg * 4 + j;
                        int jg = wc * 32 + fj * 16 + m;
                        if (ig == jg) ks = 5.0f;  // exact diagonal
                    }
                    local += ks;
                }
            }
        }
        local *= coef;
        for (int off = 32; off > 0; off >>= 1) local += __shfl_down(local, off);
        wacc += local;   // lane0 holds the wave sum
#pragma unroll
        for (int i = 0; i < 4; ++i)
#pragma unroll
            for (int j = 0; j < 2; ++j)
                acc[i][j] = (f32x4){0.f, 0.f, 0.f, 0.f};
    };

    for (int tp = 0; tp < TPB; ++tp) {
        for (int kt = 0; kt < NKT; ++kt) {
            // compute step: A from resident panel, B from staged tile-step
#pragma unroll
            for (int ks = 0; ks < 4; ++ks) {
                long af[4], bfr[2];
                int unit = (ks * 4 + kg) ^ m;      // un-swizzle on read
#pragma unroll
                for (int fi = 0; fi < 4; ++fi) {
                    int row = wr * 64 + fi * 16 + m;
                    af[fi] = *(const long*)&Al[row * D + kt * BKB + unit * 8];
                }
#pragma unroll
                for (int fj = 0; fj < 2; ++fj) {
                    int row = wc * 32 + fj * 16 + m;
                    bfr[fj] = *(const long*)&Bl[row * BKB + unit * 8];
                }
#pragma unroll
                for (int fi = 0; fi < 4; ++fi)
#pragma unroll
                    for (int fj = 0; fj < 2; ++fj)
                        acc[fi][fj] = __builtin_amdgcn_mfma_f32_16x16x32_fp8_fp8(af[fi], bfr[fj], acc[fi][fj], 0, 0, 0);
            }

            bool lastStep = (tp == TPB - 1) && (kt == NKT - 1);
            if (!lastStep) {
                __syncthreads();                   // all waves done reading Bl
                if (kt < NKT - 1) {
                    stage_B(bb, kt + 1);
                } else {
                    int bjn = bj0 + tp + 1; if (bjn > 63) bjn = 63;
                    bb = tot8 + (size_t)bjn * BM * D;
                    stage_B(bb, 0);
                    epilogue(tp);                  // overlaps B-stage flight
                }
                __syncthreads();                   // drains vmcnt(0): next B ready
            } else {
                epilogue(tp);
            }
        }
    }

    if (l == 0) atomicAdd(S, (double)wacc);
}

__global__ void finalize_kernel(const double* __restrict__ S, float* __restrict__ out) {
    out[0] = (float)(S[0] / ((double)NHALF * (double)NHALF));
}

extern "C" void kernel_launch(void* const* d_in, const int* in_sizes, int n_in,
                              void* d_out, int out_size, void* d_ws, size_t ws_size,
                              hipStream_t stream) {
    const float* src = (const float*)d_in[0];
    const float* tgt = (const float*)d_in[1];
    float* out = (float*)d_out;
    char* ws = (char*)d_ws;

    // ws layout
    unsigned char* tot8 = (unsigned char*)ws;              // 4 MB (8192*512 fp8)
    float*    sq      = (float*)(ws + 4194304);            // 32768 B
    float*    colsum  = (float*)(ws + 4194304 + 32768);    // 2048 B
    double*   sumsq   = (double*)(ws + 4194304 + 34816);   // 8 B
    double*   S       = (double*)(ws + 4194304 + 34824);   // 8 B
    unsigned* ticket  = (unsigned*)(ws + 4194304 + 34832); // 4 B
    float*    inv16bw = (float*)(ws + 4194304 + 34836);    // 4 B

    // zero colsum+sumsq+S+ticket (ws poisoned 0xAA, not re-poisoned between replays)
    hipMemsetAsync(ws + 4194304 + 32768, 0, 2068, stream);

    conv_stats<<<CONV_BLOCKS, 256, 0, stream>>>(src, tgt, tot8, sq, colsum, sumsq, ticket, inv16bw);
    mmd_main<<<NBLK, 512, 0, stream>>>(tot8, sq, inv16bw, S);
    finalize_kernel<<<1, 1, 0, stream>>>(S, out);
}

// Round 26
// 73.636 us; speedup vs baseline: 1.6585x; 1.6585x over previous
//
#include <hip/hip_runtime.h>
#include <hip/hip_fp8.h>

#define NHALF 4096
#define NROWS 8192
#define D 512
#define BM 128
#define BKB 128                    // K-depth per tile in fp8 bytes
#define NKT (D / BKB)              // 4 K-steps
#define NB (NROWS / BM)            // 64
#define NTRI (NB * (NB + 1) / 2)   // 2080 (divisible by 8)
#define CONV_BLOCKS 256

typedef float f32x4 __attribute__((ext_vector_type(4)));

__device__ __forceinline__ const float* row_ptr(const float* __restrict__ src,
                                                const float* __restrict__ tgt, int r) {
    return (r < NHALF) ? (src + (size_t)r * D) : (tgt + (size_t)(r - NHALF) * D);
}

// --- Pass A: convert fp32->fp8 e4m3 via HW v_cvt_pk_fp8_f32 (XOR-swizzle baked)
//     + rowsq + colsum + sumsq + (last block, ticketed) bandwidth scalar ---
__global__ __launch_bounds__(256)
void conv_stats(const float* __restrict__ src, const float* __restrict__ tgt,
                unsigned char* __restrict__ tot8, float* __restrict__ sq,
                float* __restrict__ colsum, double* __restrict__ sumsq,
                unsigned* __restrict__ ticket, float* __restrict__ inv16bw_out) {
    __shared__ float cs_lds[4][512];
    __shared__ float wssq[4];
    __shared__ int lastFlag;
    __shared__ double red[256];
    int t = threadIdx.x, l = t & 63, w = t >> 6;
    int rbase = blockIdx.x * 32 + w * 8;

    float cs[8] = {0.f, 0.f, 0.f, 0.f, 0.f, 0.f, 0.f, 0.f};
    float ssq = 0.f;

    for (int rr = 0; rr < 8; ++rr) {
        int r = rbase + rr;
        const float* p = row_ptr(src, tgt, r) + l * 8;
        float4 v0 = *(const float4*)p;
        float4 v1 = *(const float4*)(p + 4);
        // HW packed conversion: 8 floats -> 8 e4m3 bytes in 4 instructions
        union { unsigned long long u; int i2[2]; } q;
        q.i2[0] = __builtin_amdgcn_cvt_pk_fp8_f32(v0.x, v0.y, 0, false);
        q.i2[0] = __builtin_amdgcn_cvt_pk_fp8_f32(v0.z, v0.w, q.i2[0], true);
        q.i2[1] = __builtin_amdgcn_cvt_pk_fp8_f32(v1.x, v1.y, 0, false);
        q.i2[1] = __builtin_amdgcn_cvt_pk_fp8_f32(v1.z, v1.w, q.i2[1], true);
        unsigned dstu = (unsigned)((l & 48) | ((l & 15) ^ (r & 15)));
        *(unsigned long long*)&tot8[(size_t)r * D + dstu * 8] = q.u;

        float s8 = v0.x*v0.x + v0.y*v0.y + v0.z*v0.z + v0.w*v0.w
                 + v1.x*v1.x + v1.y*v1.y + v1.z*v1.z + v1.w*v1.w;
        ssq += s8;
        cs[0] += v0.x; cs[1] += v0.y; cs[2] += v0.z; cs[3] += v0.w;
        cs[4] += v1.x; cs[5] += v1.y; cs[6] += v1.z; cs[7] += v1.w;
        float rsum = s8;
        for (int off = 32; off > 0; off >>= 1) rsum += __shfl_down(rsum, off);
        if (l == 0) sq[r] = rsum;
    }
#pragma unroll
    for (int j = 0; j < 8; ++j) cs_lds[w][l * 8 + j] = cs[j];
    for (int off = 32; off > 0; off >>= 1) ssq += __shfl_down(ssq, off);
    if (l == 0) wssq[w] = ssq;
    __syncthreads();
    int c0 = t * 2;
    float a = cs_lds[0][c0] + cs_lds[1][c0] + cs_lds[2][c0] + cs_lds[3][c0];
    float b = cs_lds[0][c0+1] + cs_lds[1][c0+1] + cs_lds[2][c0+1] + cs_lds[3][c0+1];
    atomicAdd(&colsum[c0], a);
    atomicAdd(&colsum[c0 + 1], b);
    if (t == 0) atomicAdd(sumsq, (double)(wssq[0] + wssq[1] + wssq[2] + wssq[3]));
    __syncthreads();

    if (t == 0) {
        __threadfence();
        unsigned old = atomicAdd(ticket, 1u);
        lastFlag = (old == CONV_BLOCKS - 1) ? 1 : 0;
    }
    __syncthreads();
    if (lastFlag) {
        float ca = atomicAdd(&colsum[t], 0.f);
        float cb = atomicAdd(&colsum[t + 256], 0.f);
        red[t] = (double)ca * ca + (double)cb * cb;
        __syncthreads();
        for (int s = 128; s > 0; s >>= 1) {
            if (t < s) red[t] += red[t + s];
            __syncthreads();
        }
        if (t == 0) {
            double ssqd = atomicAdd(sumsq, 0.0);
            double m = (double)NROWS;
            double sumL2 = 2.0 * m * ssqd - 2.0 * red[0];
            double bw = sumL2 / (m * m - m) / 4.0;   // / KERNEL_MUL^(KERNEL_NUM//2)
            inv16bw_out[0] = (float)(1.0 / (16.0 * bw));
        }
    }
}

// --- Pass B: fp8 MFMA pairwise kernel, 512 thr / 8 waves, 2-barrier loop, no fences
//     (byte-identical to R18/R24's measured 42.8-42.9 us version) ---
__global__ __launch_bounds__(512, 4)
void mmd_main(const unsigned char* __restrict__ tot8,
              const float* __restrict__ sq, const float* __restrict__ inv16bw_p,
              double* __restrict__ S) {
    int b = blockIdx.x;
    int ti = (b & 7) * (NTRI / 8) + (b >> 3);   // XCD swizzle (2080 % 8 == 0)
    int bi = (int)(64.5f - sqrtf(64.5f * 64.5f - 2.0f * (float)ti));
    if (bi < 0) bi = 0;
    while (bi > 0 && bi * NB - bi * (bi - 1) / 2 > ti) --bi;
    while ((bi + 1) * NB - (bi + 1) * bi / 2 <= ti) ++bi;
    int bj = bi + (ti - (bi * NB - bi * (bi - 1) / 2));

    // LDS: row-major fp8 tile [128 rows][128 B], 8B-units XOR-swizzled (baked in global)
    __shared__ __align__(16) unsigned char As[BM * BKB];   // 16 KB
    __shared__ __align__(16) unsigned char Bs[BM * BKB];   // 16 KB

    int t = threadIdx.x, l = t & 63, w = t >> 6;
    int wr = w >> 2, wc = w & 3;       // 2x4 wave grid; per-wave 64x32 output
    int m = l & 15, kg = l >> 4;

    const unsigned char* ab = tot8 + (size_t)(bi * BM) * D;
    const unsigned char* bb = tot8 + (size_t)(bj * BM) * D;

    f32x4 acc[4][2];
#pragma unroll
    for (int i = 0; i < 4; ++i)
#pragma unroll
        for (int j = 0; j < 2; ++j)
            acc[i][j] = (f32x4){0.f, 0.f, 0.f, 0.f};

    for (int kt = 0; kt < NKT; ++kt) {
        __syncthreads();   // previous iteration's LDS reads done
        // 1024 16-B chunks per matrix; 2 per thread per matrix; verbatim copy
#pragma unroll
        for (int i = 0; i < 2; ++i) {
            int g = i * 512 + t;
            int row = g >> 3, ch = g & 7;
            __builtin_amdgcn_global_load_lds(
                (const __attribute__((address_space(1))) void*)(ab + (size_t)row * D + kt * BKB + ch * 16),
                (__attribute__((address_space(3))) void*)(As + g * 16),
                16, 0, 0);
            __builtin_amdgcn_global_load_lds(
                (const __attribute__((address_space(1))) void*)(bb + (size_t)row * D + kt * BKB + ch * 16),
                (__attribute__((address_space(3))) void*)(Bs + g * 16),
                16, 0, 0);
        }
        __syncthreads();   // drains vmcnt(0): tile ready

#pragma unroll
        for (int ks = 0; ks < 4; ++ks) {   // 4 x K=32 fp8 MFMA slices per tile
            long af[4], bfr[2];
#pragma unroll
            for (int fi = 0; fi < 4; ++fi) {
                int row = wr * 64 + fi * 16 + m;
                int unit = (ks * 4 + kg) ^ m;          // un-swizzle on read
                af[fi] = *(const long*)&As[row * BKB + unit * 8];
            }
#pragma unroll
            for (int fj = 0; fj < 2; ++fj) {
                int row = wc * 32 + fj * 16 + m;
                int unit = (ks * 4 + kg) ^ m;
                bfr[fj] = *(const long*)&Bs[row * BKB + unit * 8];
            }
#pragma unroll
            for (int fi = 0; fi < 4; ++fi)
#pragma unroll
                for (int fj = 0; fj < 2; ++fj)
                    acc[fi][fj] = __builtin_amdgcn_mfma_f32_16x16x32_fp8_fp8(af[fi], bfr[fj], acc[fi][fj], 0, 0, 0);
        }
    }

    // Epilogue: L2 -> 5-kernel sum (1 exp + 4 squarings); exact diagonal substitution
    float inv16bw = inv16bw_p[0];
    float coef = ((bi == bj) ? 1.f : 2.f) * (((bi < NB / 2) == (bj < NB / 2)) ? 1.f : -1.f);

    float sqj[2];
#pragma unroll
    for (int fj = 0; fj < 2; ++fj) sqj[fj] = sq[bj * BM + wc * 32 + fj * 16 + m];
    int ib = bi * BM + wr * 64 + kg * 4;

    float local = 0.f;
#pragma unroll
    for (int fi = 0; fi < 4; ++fi) {
        float sqi[4];
#pragma unroll
        for (int j = 0; j < 4; ++j) sqi[j] = sq[ib + fi * 16 + j];
#pragma unroll
        for (int fj = 0; fj < 2; ++fj) {
#pragma unroll
            for (int j = 0; j < 4; ++j) {
                float L2 = sqi[j] + sqj[fj] - 2.f * acc[fi][fj][j];
                float u = __expf(-L2 * inv16bw);   // e^{-t/16}
                float ks = u;
                u *= u; ks += u;   // e^{-t/8}
                u *= u; ks += u;   // e^{-t/4}
                u *= u; ks += u;   // e^{-t/2}
                u *= u; ks += u;   // e^{-t}
                if (bi == bj) {
                    int ig = wr * 64 + fi * 16 + kg * 4 + j;
                    int jg = wc * 32 + fj * 16 + m;
                    if (ig == jg) ks = 5.0f;  // exact diagonal: L2 == 0 -> 5 kernels of 1
                }
                local += ks;
            }
        }
    }
    local *= coef;

    for (int off = 32; off > 0; off >>= 1) local += __shfl_down(local, off);
    __shared__ float wsum[8];
    if (l == 0) wsum[w] = local;
    __syncthreads();
    if (t == 0) {
        float bsum = wsum[0] + wsum[1] + wsum[2] + wsum[3]
                   + wsum[4] + wsum[5] + wsum[6] + wsum[7];
        atomicAdd(S, (double)bsum);
    }
}

__global__ void finalize_kernel(const double* __restrict__ S, float* __restrict__ out) {
    out[0] = (float)(S[0] / ((double)NHALF * (double)NHALF));
}

extern "C" void kernel_launch(void* const* d_in, const int* in_sizes, int n_in,
                              void* d_out, int out_size, void* d_ws, size_t ws_size,
                              hipStream_t stream) {
    const float* src = (const float*)d_in[0];
    const float* tgt = (const float*)d_in[1];
    float* out = (float*)d_out;
    char* ws = (char*)d_ws;

    // ws layout
    unsigned char* tot8 = (unsigned char*)ws;              // 4 MB (8192*512 fp8)
    float*    sq      = (float*)(ws + 4194304);            // 32768 B
    float*    colsum  = (float*)(ws + 4194304 + 32768);    // 2048 B
    double*   sumsq   = (double*)(ws + 4194304 + 34816);   // 8 B
    double*   S       = (double*)(ws + 4194304 + 34824);   // 8 B
    unsigned* ticket  = (unsigned*)(ws + 4194304 + 34832); // 4 B
    float*    inv16bw = (float*)(ws + 4194304 + 34836);    // 4 B

    // zero colsum+sumsq+S+ticket (ws poisoned 0xAA, not re-poisoned between replays)
    hipMemsetAsync(ws + 4194304 + 32768, 0, 2068, stream);

    conv_stats<<<CONV_BLOCKS, 256, 0, stream>>>(src, tgt, tot8, sq, colsum, sumsq, ticket, inv16bw);
    mmd_main<<<NTRI, 512, 0, stream>>>(tot8, sq, inv16bw, S);
    finalize_kernel<<<1, 1, 0, stream>>>(S, out);
}